// Round 5
// baseline (219.016 us; speedup 1.0000x reference)
//
#include <hip/hip_runtime.h>
#include <stdint.h>

#define B_N   8192
#define D_K   626
#define KPAD  640        // fp8 bytes per row (padded)
#define BK    64         // K-bytes per pipeline step
#define NT    10         // KPAD / BK
#define BMN   256        // square output tile per block (R17)
#define FIN_BLOCKS 16

typedef __attribute__((ext_vector_type(4))) int   i32x4;
typedef __attribute__((ext_vector_type(8))) int   i32x8;
typedef __attribute__((ext_vector_type(16))) float f32x16;

__device__ __forceinline__ void async16(const unsigned char* g, unsigned char* l) {
    __builtin_amdgcn_global_load_lds(
        (const __attribute__((address_space(1))) unsigned int*)(const void*)g,
        (__attribute__((address_space(3))) unsigned int*)(void*)l,
        16, 0, 0);
}

// ---------------- Kernel 1: row-normalize + convert to fp8 e4m3 (padded K) --
// R13: 2 rows/wave, 2048 blocks = 8 blocks/CU -> full occupancy.
__global__ __launch_bounds__(256) void normalize_kernel(
    const float* __restrict__ A, const float* __restrict__ P,
    unsigned char* __restrict__ Af8, unsigned char* __restrict__ Pf8,
    float* __restrict__ rowexp, float* __restrict__ rowsum, float* __restrict__ acc)
{
    const int which = blockIdx.y;
    const float* srcM = which ? P : A;
    unsigned char* dstM = which ? Pf8 : Af8;
    const int t  = threadIdx.x;
    const int wv = t >> 6;
    const int L  = t & 63;
    const int rowBase = blockIdx.x * 8 + wv * 2;

    if (which == 0) {
        const int rb = blockIdx.x * 8;
        if (t < 8) { rowexp[rb + t] = 0.0f; rowsum[rb + t] = 0.0f; }
        if (blockIdx.x == 0 && t < 4) acc[t] = 0.0f;   // acc[3] = finalize done-counter
    }

    #pragma unroll
    for (int j = 0; j < 2; ++j) {
        const int r = rowBase + j;
        const float2* s2 = (const float2*)(srcM + (size_t)r * D_K);

        float2 a0 = s2[2 * L];       float2 a1 = s2[2 * L + 1];       // ints 0..63
        float2 b0 = s2[2 * L + 128]; float2 b1 = s2[2 * L + 129];     // ints 64..127
        float2 c0 = {0.f, 0.f},      c1 = {0.f, 0.f};                 // ints 128..159
        if (L < 28)       { c0 = s2[2 * L + 256]; c1 = s2[2 * L + 257]; }
        else if (L == 28) { c0 = s2[312]; }                            // floats 624,625

        float ss = a0.x * a0.x + a0.y * a0.y + a1.x * a1.x + a1.y * a1.y
                 + b0.x * b0.x + b0.y * b0.y + b1.x * b1.x + b1.y * b1.y
                 + c0.x * c0.x + c0.y * c0.y + c1.x * c1.x + c1.y * c1.y;
        #pragma unroll
        for (int off = 32; off; off >>= 1) ss += __shfl_xor(ss, off, 64);
        const float rn = rsqrtf(ss);   // norms ~25, eps never active

        int* d4 = (int*)(dstM + (size_t)r * KPAD);
        int pk0 = __builtin_amdgcn_cvt_pk_fp8_f32(a0.x * rn, a0.y * rn, 0, false);
        pk0 = __builtin_amdgcn_cvt_pk_fp8_f32(a1.x * rn, a1.y * rn, pk0, true);
        d4[L] = pk0;
        int pk1 = __builtin_amdgcn_cvt_pk_fp8_f32(b0.x * rn, b0.y * rn, 0, false);
        pk1 = __builtin_amdgcn_cvt_pk_fp8_f32(b1.x * rn, b1.y * rn, pk1, true);
        d4[L + 64] = pk1;
        if (L < 32) {
            int pk2 = __builtin_amdgcn_cvt_pk_fp8_f32(c0.x * rn, c0.y * rn, 0, false);
            pk2 = __builtin_amdgcn_cvt_pk_fp8_f32(c1.x * rn, c1.y * rn, pk2, true);
            d4[L + 128] = pk2;
        }
    }
}

// ---------------- Kernel 2: fused fp8 cosine-GEMM + row reductions ----------
// R17: full 8-phase-template port (m201 structure).
// R16 post-mortem (87.5 us > R14's 74.7): coarse counted-vmcnt without the
//   per-phase interleave = m196's predicted -7..-27% regression. With 2
//   blocks/CU the cross-block TLP already hides the 2-phase drain (m114);
//   the only measured path past it is the FULL 8-phase form (regime-gate
//   m228d/m230): per-phase {ds-read subtile, stage-issue, barrier, lgkm0,
//   MFMA cluster, barrier}, vmcnt counted ONCE per K-step, 256^2 tile,
//   8 waves, 1 block/CU.
// Structure: 512 thr (wave grid 4 row x 2 col, 64x128 out/wave: 2mi x 4ni =
//   8 MFMA, 6 frag-reads/step = 0.75 reads/MFMA). BK=64, THREE buffers
//   (96 KB), stage(s+2) split A->phase1, B->phase2. Top-of-step
//   s_waitcnt vmcnt(4) retires stage(s) exactly (outstanding = stage(s) 4 +
//   stage(s+1) 4; issue order A,A,B,B per step, in-order retirement);
//   vmcnt(0) only at the last step. Rule #18: lgkmcnt(0) asm is followed by
//   sched_barrier(0) so MFMAs can't hoist past it.
// WAR safety: stage(s+2) writes buf[(s-1)%3], whose reads (step s-1) were
//   drained by that step's lgkm0 before its waves entered step s's top
//   barrier; stage(s+2) issues after that barrier.
// LDS geometry: R16's HW-VALIDATED zero-conflict scheme, verbatim: two 64-B
//   rows per 128-B superrow (stride = 32 banks), 8x16B slots, key(sr) =
//   (sr&7)^((sr>>3)&1) on stage source AND read (involution, rule #21).
// Grid map (assumes bid%8 -> XCD, m09/m192): XCD x owns an 8-row x 16-col
//   block region; resident window = 2 A-panels + 16 B-panels = 2.9 MB < 4 MB
//   L2. Predicted FETCH ~31 MB (A x2, B x4 amplification).
// Ledger (do NOT retry):
//  - R8: min-waves=4 @128^2 -> 64 VGPR -> scratch spill (2x)
//  - R9/R16: BK=64 without per-phase interleave -> slower (m196 class)
//  - R10: fused exit-path __threadfence -> L2 writeback storm (2x)
//  - R12: A direct global->VGPR -> in-order vmcnt drains B prefetch (2x)
//  - R14: swizzle alone under 2-phase drain: conflicts->0, time ~0 (gated)
//  - R15: same-B-panel-on-all-XCDs mapping: FETCH 3.6x, latency-bound (2.9x)
__global__ __launch_bounds__(512, 2) void gemm_fused_kernel(
    const unsigned char* __restrict__ Af8, const unsigned char* __restrict__ Pf8,
    float* __restrict__ rowexp, float* __restrict__ rowsum, float* __restrict__ diag)
{
    __shared__ __align__(16) unsigned char sA[3][BMN * BK];   // 48 KB
    __shared__ __align__(16) unsigned char sB[3][BMN * BK];   // 48 KB

    const int t    = threadIdx.x;     // 0..511
    const int lane = t & 63;
    const int w    = t >> 6;          // 0..7
    const int wr   = w >> 1;          // 0..3: rows wr*64..+63
    const int wc   = w & 1;           // 0..1: cols wc*128..+127
    const int rA   = lane & 31;
    const int h    = lane >> 5;       // K-half selector
    const int par4 = (rA & 1) * 4;    // row parity -> slot half within superrow

    // XCD-aware 2D-chunked mapping (bid%8 -> XCD assumed round-robin)
    const int bid = blockIdx.x;               // 0..1023
    const int xcd = bid & 7, kk = bid >> 3;   // kk = 0..127
    const int br  = (xcd >> 1) * 8 + (kk >> 4);    // 0..31
    const int bc  = (xcd & 1) * 16 + (kk & 15);    // 0..31
    const int rowBase = br * BMN;
    const int colBase = bc * BMN;

    const unsigned char* Ab = Af8 + (size_t)rowBase * KPAD;
    const unsigned char* Pb = Pf8 + (size_t)colBase * KPAD;

    // staging: 1024 16-B chunks per matrix per step (128 superrows x 8 slots);
    // 2 chunks/matrix/thread. LDS dest linear; source slot = p ^ key(sr).
    const int q0 = t, q1 = t + 512;
    const int sr0 = q0 >> 3, sr1 = q1 >> 3;
    const int l0 = (q0 & 7) ^ ((sr0 & 7) ^ ((sr0 >> 3) & 1));
    const int l1 = (q1 & 7) ^ ((sr1 & 7) ^ ((sr1 >> 3) & 1));
    const size_t gOff0 = (size_t)(2 * sr0 + (l0 >> 2)) * KPAD + (size_t)((l0 & 3) * 16);
    const size_t gOff1 = (size_t)(2 * sr1 + (l1 >> 2)) * KPAD + (size_t)((l1 & 3) * 16);

    auto stageA = [&](int buf, int kt) {
        const unsigned char* s = Ab + (size_t)kt * BK;
        async16(s + gOff0, &sA[buf][q0 * 16]);
        async16(s + gOff1, &sA[buf][q1 * 16]);
    };
    auto stageB = [&](int buf, int kt) {
        const unsigned char* s = Pb + (size_t)kt * BK;
        async16(s + gOff0, &sB[buf][q0 * 16]);
        async16(s + gOff1, &sB[buf][q1 * 16]);
    };

    auto loadFragA = [&](int buf, int mi) -> i32x8 {
        const int sr  = wr * 32 + mi * 16 + (rA >> 1);
        const int key = (sr & 7) ^ ((sr >> 3) & 1);
        const int s0  = ((par4 + 2 * h) ^ key) * 16;
        const unsigned char* base = &sA[buf][sr * 128];
        i32x4 lo = *(const i32x4*)(base + s0);
        i32x4 hi = *(const i32x4*)(base + (s0 ^ 16));
        return __builtin_shufflevector(lo, hi, 0, 1, 2, 3, 4, 5, 6, 7);
    };
    auto loadFragB = [&](int buf, int ni) -> i32x8 {
        const int sr  = wc * 64 + ni * 16 + (rA >> 1);
        const int key = (sr & 7) ^ ((sr >> 3) & 1);
        const int s0  = ((par4 + 2 * h) ^ key) * 16;
        const unsigned char* base = &sB[buf][sr * 128];
        i32x4 lo = *(const i32x4*)(base + s0);
        i32x4 hi = *(const i32x4*)(base + (s0 ^ 16));
        return __builtin_shufflevector(lo, hi, 0, 1, 2, 3, 4, 5, 6, 7);
    };

    f32x16 acc[2][4];   // [mi][ni], each 32x32
    const f32x16 z16 = {0.f,0.f,0.f,0.f,0.f,0.f,0.f,0.f,
                        0.f,0.f,0.f,0.f,0.f,0.f,0.f,0.f};
    #pragma unroll
    for (int mi = 0; mi < 2; ++mi)
        #pragma unroll
        for (int ni = 0; ni < 4; ++ni) acc[mi][ni] = z16;

    // prologue: depth-2 prefetch (issue order per step: A,A,B,B)
    stageA(0, 0); stageB(0, 0);
    stageA(1, 1); stageB(1, 1);

    int buf = 0;
    #pragma unroll 1
    for (int s = 0; s < NT; ++s) {
        if (s < NT - 1) asm volatile("s_waitcnt vmcnt(4)" ::: "memory");
        else            asm volatile("s_waitcnt vmcnt(0)" ::: "memory");
        __builtin_amdgcn_s_barrier();

        const bool pre = (s + 2 < NT);
        int sb = buf - 1; if (sb < 0) sb = 2;   // (s+2) % 3

        // ---- phase 1: A frags + B frags 0,1 / stage A(s+2) / MFMA quad 1 ----
        i32x8 aF0 = loadFragA(buf, 0);
        i32x8 aF1 = loadFragA(buf, 1);
        i32x8 bF0 = loadFragB(buf, 0);
        i32x8 bF1 = loadFragB(buf, 1);
        if (pre) stageA(sb, s + 2);
        __builtin_amdgcn_s_barrier();
        asm volatile("s_waitcnt lgkmcnt(0)" ::: "memory");
        __builtin_amdgcn_sched_barrier(0);
        __builtin_amdgcn_s_setprio(1);
        acc[0][0] = __builtin_amdgcn_mfma_scale_f32_32x32x64_f8f6f4(
            aF0, bF0, acc[0][0], 0, 0, 0, 0x7F, 0, 0x7F);
        acc[0][1] = __builtin_amdgcn_mfma_scale_f32_32x32x64_f8f6f4(
            aF0, bF1, acc[0][1], 0, 0, 0, 0x7F, 0, 0x7F);
        acc[1][0] = __builtin_amdgcn_mfma_scale_f32_32x32x64_f8f6f4(
            aF1, bF0, acc[1][0], 0, 0, 0, 0x7F, 0, 0x7F);
        acc[1][1] = __builtin_amdgcn_mfma_scale_f32_32x32x64_f8f6f4(
            aF1, bF1, acc[1][1], 0, 0, 0, 0x7F, 0, 0x7F);
        __builtin_amdgcn_s_setprio(0);
        __builtin_amdgcn_s_barrier();

        // ---- phase 2: B frags 2,3 / stage B(s+2) / MFMA quad 2 -------------
        i32x8 bF2 = loadFragB(buf, 2);
        i32x8 bF3 = loadFragB(buf, 3);
        if (pre) stageB(sb, s + 2);
        __builtin_amdgcn_s_barrier();
        asm volatile("s_waitcnt lgkmcnt(0)" ::: "memory");
        __builtin_amdgcn_sched_barrier(0);
        __builtin_amdgcn_s_setprio(1);
        acc[0][2] = __builtin_amdgcn_mfma_scale_f32_32x32x64_f8f6f4(
            aF0, bF2, acc[0][2], 0, 0, 0, 0x7F, 0, 0x7F);
        acc[0][3] = __builtin_amdgcn_mfma_scale_f32_32x32x64_f8f6f4(
            aF0, bF3, acc[0][3], 0, 0, 0, 0x7F, 0, 0x7F);
        acc[1][2] = __builtin_amdgcn_mfma_scale_f32_32x32x64_f8f6f4(
            aF1, bF2, acc[1][2], 0, 0, 0, 0x7F, 0, 0x7F);
        acc[1][3] = __builtin_amdgcn_mfma_scale_f32_32x32x64_f8f6f4(
            aF1, bF3, acc[1][3], 0, 0, 0, 0x7F, 0, 0x7F);
        __builtin_amdgcn_s_setprio(0);
        // closing barrier of this step = next iteration's top barrier

        ++buf; if (buf == 3) buf = 0;
    }

    // ----- epilogue: registers only ------------------------------------
    // C/D layout: col = rA, row = (rg&3) + 8*(rg>>2) + 4*h  (verified R13-R16)
    if (rowBase == colBase) {   // diagonal block
        #pragma unroll
        for (int mi = 0; mi < 2; ++mi)
            #pragma unroll
            for (int ni = 0; ni < 4; ++ni)
                if (wr * 64 + mi * 32 == wc * 128 + ni * 32) {  // wave-uniform
                    #pragma unroll
                    for (int rg = 0; rg < 16; ++rg) {
                        const int row32 = (rg & 3) + 8 * (rg >> 2) + 4 * h;
                        if (rA == row32)
                            diag[rowBase + wr * 64 + mi * 32 + row32] = acc[mi][ni][rg];
                    }
                }
    }

    #pragma unroll
    for (int mi = 0; mi < 2; ++mi) {
        #pragma unroll
        for (int rg = 0; rg < 16; ++rg) {
            float sv = acc[mi][0][rg] + acc[mi][1][rg]
                     + acc[mi][2][rg] + acc[mi][3][rg];
            float ev = __expf(acc[mi][0][rg] * 4.0f) + __expf(acc[mi][1][rg] * 4.0f)
                     + __expf(acc[mi][2][rg] * 4.0f) + __expf(acc[mi][3][rg] * 4.0f);
            #pragma unroll
            for (int off = 1; off <= 16; off <<= 1) {   // reduce 32 cols, keep h
                sv += __shfl_xor(sv, off, 64);
                ev += __shfl_xor(ev, off, 64);
            }
            if (rA == 0) {   // lanes 0 / 32 hold h=0 / h=1 row groups
                const int gr = rowBase + wr * 64 + mi * 32
                             + (rg & 3) + 8 * (rg >> 2) + 4 * h;
                atomicAdd(&rowsum[gr], sv);
                atomicAdd(&rowexp[gr], ev);
            }
        }
    }
}

// ---------------- Kernel 3: final reduction + device-side completion --------
__global__ __launch_bounds__(256) void finalize_kernel(
    const float* __restrict__ rowexp, const float* __restrict__ rowsum,
    const float* __restrict__ diag, float* __restrict__ acc, float* __restrict__ out)
{
    const int t = threadIdx.x;
    float ls = 0.f, ds = 0.f, ns = 0.f;
    for (int i = blockIdx.x * 256 + t; i < B_N; i += FIN_BLOCKS * 256) {
        const float d = diag[i];
        ls += __logf(rowexp[i]) - d * 4.0f;   // logsumexp - diag_logit
        ds += d;
        ns += (rowsum[i] - d);
    }
    #pragma unroll
    for (int off = 32; off; off >>= 1) {
        ls += __shfl_down(ls, off, 64);
        ds += __shfl_down(ds, off, 64);
        ns += __shfl_down(ns, off, 64);
    }
    __shared__ float sl[4], sd[4], sn[4];
    if ((t & 63) == 0) { sl[t >> 6] = ls; sd[t >> 6] = ds; sn[t >> 6] = ns; }
    __syncthreads();
    if (t == 0) {
        atomicAdd(acc + 0, sl[0] + sl[1] + sl[2] + sl[3]);
        atomicAdd(acc + 1, sd[0] + sd[1] + sd[2] + sd[3]);
        atomicAdd(acc + 2, sn[0] + sn[1] + sn[2] + sn[3]);
        __threadfence();
        const int done = (int)atomicAdd((unsigned int*)(acc + 3), 1u);
        if (done == FIN_BLOCKS - 1) {
            const float L  = atomicAdd(acc + 0, 0.0f);   // coherent reads
            const float Dm = atomicAdd(acc + 1, 0.0f);
            const float Nn = atomicAdd(acc + 2, 0.0f);
            out[0] = L / (float)B_N;
            out[1] = Dm / (float)B_N;
            out[2] = (Nn / (float)(B_N - 1)) / (float)B_N;
        }
    }
}

// ---------------- Fallback path (small workspace): fp32 vector --------------
__global__ __launch_bounds__(256) void fb_norm(
    const float* __restrict__ A, const float* __restrict__ P,
    float* __restrict__ rna, float* __restrict__ rnp, float* __restrict__ acc)
{
    const int r = blockIdx.x;
    const float* src = blockIdx.y ? P : A;
    const int t = threadIdx.x;
    float ss = 0.f;
    for (int k = t; k < D_K; k += 256) { float v = src[(size_t)r * D_K + k]; ss += v * v; }
    #pragma unroll
    for (int off = 32; off; off >>= 1) ss += __shfl_down(ss, off, 64);
    __shared__ float sred[4];
    if ((t & 63) == 0) sred[t >> 6] = ss;
    __syncthreads();
    if (t == 0) {
        const float rn = rsqrtf(sred[0] + sred[1] + sred[2] + sred[3]);
        (blockIdx.y ? rnp : rna)[r] = rn;
    }
    if (blockIdx.x == 0 && blockIdx.y == 0 && t < 3) acc[t] = 0.0f;
}

__global__ __launch_bounds__(256) void fb_main(
    const float* __restrict__ A, const float* __restrict__ P,
    const float* __restrict__ rna, const float* __restrict__ rnp,
    float* __restrict__ acc)
{
    __shared__ float sa[D_K];
    __shared__ float red[12];
    const int i = blockIdx.x;
    const int t = threadIdx.x;
    const float rn = rna[i];
    for (int k = t; k < D_K; k += 256) sa[k] = A[(size_t)i * D_K + k] * rn;
    __syncthreads();
    const int w = t >> 6, lane = t & 63;
    float we = 0.f, wsum = 0.f, wd = 0.f;
    for (int j = w; j < B_N; j += 4) {
        float dot = 0.f;
        const float* p = P + (size_t)j * D_K;
        for (int k = lane; k < D_K; k += 64) dot += sa[k] * p[k];
        #pragma unroll
        for (int off = 32; off; off >>= 1) dot += __shfl_xor(dot, off, 64);
        const float S = dot * rnp[j];
        we += __expf(S * 4.0f);
        wsum += S;
        if (j == i) wd = S;
    }
    if (lane == 0) { red[w] = we; red[4 + w] = wsum; red[8 + w] = wd; }
    __syncthreads();
    if (t == 0) {
        const float E  = red[0] + red[1] + red[2] + red[3];
        const float Sm = red[4] + red[5] + red[6] + red[7];
        const float Dd = red[8] + red[9] + red[10] + red[11];
        atomicAdd(acc + 0, __logf(E) - 4.0f * Dd);
        atomicAdd(acc + 1, Dd);
        atomicAdd(acc + 2, Sm - Dd);
    }
}

__global__ void fb_fin(const float* __restrict__ acc, float* __restrict__ out)
{
    out[0] = acc[0] / (float)B_N;
    out[1] = acc[1] / (float)B_N;
    out[2] = acc[2] / ((float)(B_N - 1) * (float)B_N);
}

// ---------------------------------------------------------------------------
extern "C" void kernel_launch(void* const* d_in, const int* in_sizes, int n_in,
                              void* d_out, int out_size, void* d_ws, size_t ws_size,
                              hipStream_t stream)
{
    const float* A = (const float*)d_in[0];
    const float* P = (const float*)d_in[1];
    float* out = (float*)d_out;
    char* ws = (char*)d_ws;

    const size_t AF8_OFF  = 0;
    const size_t PF8_OFF  = AF8_OFF + (size_t)B_N * KPAD;
    const size_t REXP_OFF = PF8_OFF + (size_t)B_N * KPAD;
    const size_t RSUM_OFF = REXP_OFF + (size_t)B_N * sizeof(float);
    const size_t DIAG_OFF = RSUM_OFF + (size_t)B_N * sizeof(float);
    const size_t ACC_OFF  = DIAG_OFF + (size_t)B_N * sizeof(float);
    const size_t MAIN_REQ = ACC_OFF + 16;

    if (ws_size >= MAIN_REQ) {
        unsigned char* Af8 = (unsigned char*)(ws + AF8_OFF);
        unsigned char* Pf8 = (unsigned char*)(ws + PF8_OFF);
        float* rowexp = (float*)(ws + REXP_OFF);
        float* rowsum = (float*)(ws + RSUM_OFF);
        float* diag   = (float*)(ws + DIAG_OFF);
        float* acc    = (float*)(ws + ACC_OFF);

        normalize_kernel<<<dim3(B_N / 8, 2), 256, 0, stream>>>(A, P, Af8, Pf8,
                                                               rowexp, rowsum, acc);
        gemm_fused_kernel<<<dim3((B_N / BMN) * (B_N / BMN)), 512, 0, stream>>>(
            Af8, Pf8, rowexp, rowsum, diag);
        finalize_kernel<<<FIN_BLOCKS, 256, 0, stream>>>(rowexp, rowsum, diag, acc, out);
    } else {
        // slow-but-correct fp32 fallback (needs ~96 KB ws)
        float* rna = (float*)ws;
        float* rnp = rna + B_N;
        float* acc = rnp + B_N;
        fb_norm<<<dim3(B_N, 2), 256, 0, stream>>>(A, P, rna, rnp, acc);
        fb_main<<<B_N, 256, 0, stream>>>(A, P, rna, rnp, acc);
        fb_fin<<<1, 1, 0, stream>>>(acc, out);
    }
}

// Round 6
// 162.018 us; speedup vs baseline: 1.3518x; 1.3518x over previous
//
#include <hip/hip_runtime.h>
#include <stdint.h>

#define B_N   8192
#define D_K   626
#define KPAD  640        // fp8 bytes per row (padded)
#define BK    64         // K-bytes per step (R18)
#define KSTEPS_CT 10     // K-steps per col-tile (KPAD/BK)
#define BM    128
#define BN    128
#define COL_CHUNKS 16
#define TILES_PER_CHUNK 4   // 8192 / (16*128)
#define NSTEPS 40           // TILES_PER_CHUNK * KSTEPS_CT
#define FIN_BLOCKS 16

typedef __attribute__((ext_vector_type(4))) int   i32x4;
typedef __attribute__((ext_vector_type(8))) int   i32x8;
typedef __attribute__((ext_vector_type(16))) float f32x16;

__device__ __forceinline__ void async16(const unsigned char* g, unsigned char* l) {
    __builtin_amdgcn_global_load_lds(
        (const __attribute__((address_space(1))) unsigned int*)(const void*)g,
        (__attribute__((address_space(3))) unsigned int*)(void*)l,
        16, 0, 0);
}

// ---------------- Kernel 1: row-normalize + convert to fp8 e4m3 (padded K) --
// R13: 2 rows/wave, 2048 blocks = 8 blocks/CU -> full occupancy.
// (R17 analysis: dur_us = gemm + ~76 us ADDITIVE constant across 6 rounds;
//  constant is harness reset/launch overhead, not this kernel.)
__global__ __launch_bounds__(256) void normalize_kernel(
    const float* __restrict__ A, const float* __restrict__ P,
    unsigned char* __restrict__ Af8, unsigned char* __restrict__ Pf8,
    float* __restrict__ rowexp, float* __restrict__ rowsum, float* __restrict__ acc)
{
    const int which = blockIdx.y;
    const float* srcM = which ? P : A;
    unsigned char* dstM = which ? Pf8 : Af8;
    const int t  = threadIdx.x;
    const int wv = t >> 6;
    const int L  = t & 63;
    const int rowBase = blockIdx.x * 8 + wv * 2;

    if (which == 0) {
        const int rb = blockIdx.x * 8;
        if (t < 8) { rowexp[rb + t] = 0.0f; rowsum[rb + t] = 0.0f; }
        if (blockIdx.x == 0 && t < 4) acc[t] = 0.0f;   // acc[3] = finalize done-counter
    }

    #pragma unroll
    for (int j = 0; j < 2; ++j) {
        const int r = rowBase + j;
        const float2* s2 = (const float2*)(srcM + (size_t)r * D_K);

        float2 a0 = s2[2 * L];       float2 a1 = s2[2 * L + 1];       // ints 0..63
        float2 b0 = s2[2 * L + 128]; float2 b1 = s2[2 * L + 129];     // ints 64..127
        float2 c0 = {0.f, 0.f},      c1 = {0.f, 0.f};                 // ints 128..159
        if (L < 28)       { c0 = s2[2 * L + 256]; c1 = s2[2 * L + 257]; }
        else if (L == 28) { c0 = s2[312]; }                            // floats 624,625

        float ss = a0.x * a0.x + a0.y * a0.y + a1.x * a1.x + a1.y * a1.y
                 + b0.x * b0.x + b0.y * b0.y + b1.x * b1.x + b1.y * b1.y
                 + c0.x * c0.x + c0.y * c0.y + c1.x * c1.x + c1.y * c1.y;
        #pragma unroll
        for (int off = 32; off; off >>= 1) ss += __shfl_xor(ss, off, 64);
        const float rn = rsqrtf(ss);   // norms ~25, eps never active

        int* d4 = (int*)(dstM + (size_t)r * KPAD);
        int pk0 = __builtin_amdgcn_cvt_pk_fp8_f32(a0.x * rn, a0.y * rn, 0, false);
        pk0 = __builtin_amdgcn_cvt_pk_fp8_f32(a1.x * rn, a1.y * rn, pk0, true);
        d4[L] = pk0;
        int pk1 = __builtin_amdgcn_cvt_pk_fp8_f32(b0.x * rn, b0.y * rn, 0, false);
        pk1 = __builtin_amdgcn_cvt_pk_fp8_f32(b1.x * rn, b1.y * rn, pk1, true);
        d4[L + 64] = pk1;
        if (L < 32) {
            int pk2 = __builtin_amdgcn_cvt_pk_fp8_f32(c0.x * rn, c0.y * rn, 0, false);
            pk2 = __builtin_amdgcn_cvt_pk_fp8_f32(c1.x * rn, c1.y * rn, pk2, true);
            d4[L + 128] = pk2;
        }
    }
}

// ---------------- Kernel 2: fused fp8 cosine-GEMM + row reductions ----------
// R18: 3-blocks/CU TLP experiment inside the PROVEN 2-phase structure.
// R17 post-mortem (142.5 us, MfmaUtil 11.7%): 8-phase port with 4-MFMA
//   clusters + 1 block/CU = lockstep barriers with nothing to overlap;
//   locality was fine (FETCH 15.5 MB). Third structural rewrite to lose to
//   R14's 74.7 -> the fine-grained-schedule path is closed in this session.
// R18 mechanism: the 2-phase drain stall (~55% of step time) is hidden by
//   CROSS-BLOCK wave overlap (m114). R14 = 2 blocks/CU (64 KB LDS). Shrink
//   to BK=64 double-buffer (32 KB/block) -> 3 blocks/CU (reg-capped:
//   92 VGPR + 64 AGPR = 156/wave -> 3 waves/SIMD; launch_bounds(256,3)).
//   R9's "BK=64 2x slower" was measured at PINNED 2 blocks/CU where halving
//   BK only doubles drain frequency; the occupancy term is the new variable.
// Geometry: R16's HW-VALIDATED zero-conflict superrow scheme at BK=64,
//   verbatim (two 64-B rows per 128-B superrow, 8x16B slots, key(sr) =
//   (sr&7)^((sr>>3)&1) on stage source AND read; involution, rule #21).
// Loop: R14's proven flow - __syncthreads (compiler vmcnt0 drain), issue
//   next-step staging, compute current. No setprio (m190: hurts 2-phase).
// Ledger (do NOT retry):
//  - R8: forcing occupancy past reg budget -> scratch spill (2x)
//  - R10: fused exit-path __threadfence -> L2 writeback storm (2x)
//  - R12: A direct global->VGPR -> in-order vmcnt drains B prefetch (2x)
//  - R14: swizzle alone under 2-phase drain: conflicts->0, time ~0 (gated)
//  - R15: same-B-panel-on-all-XCDs mapping: FETCH 3.6x, latency-bound (2.9x)
//  - R16: coarse counted-vmcnt (no per-phase interleave): -17% (m196 class)
//  - R17: 8-phase port w/ small MFMA clusters @1 block/CU: -90%
__global__ __launch_bounds__(256, 3) void gemm_fused_kernel(
    const unsigned char* __restrict__ Af8, const unsigned char* __restrict__ Pf8,
    float* __restrict__ rowexp, float* __restrict__ rowsum, float* __restrict__ diag)
{
    __shared__ __align__(16) unsigned char sA[2][BM * BK];   // 16 KB
    __shared__ __align__(16) unsigned char sB[2][BN * BK];   // 16 KB

    const int t    = threadIdx.x;
    const int lane = t & 63;
    const int w    = t >> 6;
    const int wr   = w >> 1;      // wave row (0..1): rows wr*64..+63
    const int wc   = w & 1;       // wave col (0..1): cols wc*64..+63
    const int rA   = lane & 31;   // row within a 32-row block
    const int h    = lane >> 5;   // K-half selector (which 32 of the 64 k-bytes)
    const int par4 = (rA & 1) * 4;          // row parity -> logical slot half
    const int srA0 = wr * 32 + (rA >> 1);   // superrow for mi=0 (A side)
    const int srB0 = wc * 32 + (rA >> 1);   // superrow for ni=0 (B side)

    const int rowBase = blockIdx.x * BM;       // 64 row-tiles
    const int chunk   = blockIdx.y;            // 16 col-chunks

    const unsigned char* Ab = Af8 + (size_t)rowBase * KPAD;
    const unsigned char* PbChunk = Pf8 + (size_t)(chunk * TILES_PER_CHUNK) * BN * KPAD;

    // staging: per matrix per step 512 chunks of 16 B (64 superrows x 8 slots);
    // 2 chunks/thread. LDS dest linear (q*16); source slot = p ^ key(sr).
    const int q0 = t, q1 = t + 256;
    const int sr0 = q0 >> 3, p0s = q0 & 7;
    const int sr1 = q1 >> 3, p1s = q1 & 7;
    const int l0 = p0s ^ ((sr0 & 7) ^ ((sr0 >> 3) & 1));
    const int l1 = p1s ^ ((sr1 & 7) ^ ((sr1 >> 3) & 1));
    const int gA0 = (2 * sr0 + (l0 >> 2)) * KPAD + (l0 & 3) * 16;
    const int gA1 = (2 * sr1 + (l1 >> 2)) * KPAD + (l1 & 3) * 16;

    auto stage = [&](int buf, int ct, int ks) {
        const unsigned char* AbT = Ab + ks * BK;
        const unsigned char* PbT = PbChunk + (size_t)ct * BN * KPAD + ks * BK;
        async16(AbT + gA0, &sA[buf][q0 * 16]);
        async16(AbT + gA1, &sA[buf][q1 * 16]);
        async16(PbT + gA0, &sB[buf][q0 * 16]);
        async16(PbT + gA1, &sB[buf][q1 * 16]);
    };

    // persistent per-lane row partials: [mi][reg]
    float psum[2][16], pexp[2][16];
    #pragma unroll
    for (int i = 0; i < 2; ++i)
        #pragma unroll
        for (int j = 0; j < 16; ++j) { psum[i][j] = 0.0f; pexp[i][j] = 0.0f; }

    const f32x16 z16 = {0.f,0.f,0.f,0.f,0.f,0.f,0.f,0.f,
                        0.f,0.f,0.f,0.f,0.f,0.f,0.f,0.f};
    f32x16 acc[2][2];   // [mi][ni], each 32x32
    acc[0][0] = z16; acc[0][1] = z16; acc[1][0] = z16; acc[1][1] = z16;

    auto compute = [&](int buf) {
        i32x8 aF[2], bF[2];
        #pragma unroll
        for (int mi = 0; mi < 2; ++mi) {
            const int sr  = srA0 + mi * 16;
            const int key = (sr & 7) ^ ((sr >> 3) & 1);
            const int s0  = ((par4 + 2 * h) ^ key) * 16;
            const unsigned char* base = &sA[buf][sr * 128];
            i32x4 lo = *(const i32x4*)(base + s0);
            i32x4 hi = *(const i32x4*)(base + (s0 ^ 16));
            aF[mi] = __builtin_shufflevector(lo, hi, 0, 1, 2, 3, 4, 5, 6, 7);
        }
        #pragma unroll
        for (int ni = 0; ni < 2; ++ni) {
            const int sr  = srB0 + ni * 16;
            const int key = (sr & 7) ^ ((sr >> 3) & 1);
            const int s0  = ((par4 + 2 * h) ^ key) * 16;
            const unsigned char* base = &sB[buf][sr * 128];
            i32x4 lo = *(const i32x4*)(base + s0);
            i32x4 hi = *(const i32x4*)(base + (s0 ^ 16));
            bF[ni] = __builtin_shufflevector(lo, hi, 0, 1, 2, 3, 4, 5, 6, 7);
        }
        #pragma unroll
        for (int mi = 0; mi < 2; ++mi)
            #pragma unroll
            for (int ni = 0; ni < 2; ++ni)
                acc[mi][ni] = __builtin_amdgcn_mfma_scale_f32_32x32x64_f8f6f4(
                    aF[mi], bF[ni], acc[mi][ni],
                    0 /*A: fp8 e4m3*/, 0 /*B: fp8 e4m3*/,
                    0, 0x7F /*scaleA=2^0*/, 0, 0x7F /*scaleB=2^0*/);
    };

    auto epilogue = [&](int cct) {
        const int colBase = (chunk * TILES_PER_CHUNK + cct) * BN;
        // C/D layout: col = rA, row = (rg&3) + 8*(rg>>2) + 4*h  (verified R13-R17)
        if (rowBase == colBase && wr == wc) {   // diagonal sub-blocks: ni == mi
            #pragma unroll
            for (int mi = 0; mi < 2; ++mi)
                #pragma unroll
                for (int rg = 0; rg < 16; ++rg) {
                    const int row32 = (rg & 3) + 8 * (rg >> 2) + 4 * h;
                    if (rA == row32)
                        diag[rowBase + wr * 64 + mi * 32 + row32] = acc[mi][mi][rg];
                }
        }
        #pragma unroll
        for (int mi = 0; mi < 2; ++mi) {
            #pragma unroll
            for (int rg = 0; rg < 16; ++rg) {
                const float S0 = acc[mi][0][rg];
                const float S1 = acc[mi][1][rg];
                psum[mi][rg] += S0 + S1;
                pexp[mi][rg] += __expf(S0 * 4.0f) + __expf(S1 * 4.0f);  // logits=S/0.25
            }
        }
        acc[0][0] = z16; acc[0][1] = z16; acc[1][0] = z16; acc[1][1] = z16;
    };

    // prologue: stage step 0 into buffer 0
    stage(0, 0, 0);

    int sct = 0, sks = 1;   // coords of next stage target (step s+1)
    int cct = 0, cks = 0;   // compute col-tile progress
    #pragma unroll 1
    for (int s = 0; s < NSTEPS; ++s) {
        __syncthreads();    // buf[s&1] ready (compiler drains vmcnt before barrier)
        if (s + 1 < NSTEPS) {
            stage((s + 1) & 1, sct, sks);
            if (++sks == KSTEPS_CT) { sks = 0; ++sct; }
        }
        compute(s & 1);
        if (++cks == KSTEPS_CT) { cks = 0; epilogue(cct); ++cct; }
    }

    // reduce across the 32 columns (rA lanes; offsets <=16 preserve the h bit)
    #pragma unroll
    for (int off = 1; off <= 16; off <<= 1) {
        #pragma unroll
        for (int mi = 0; mi < 2; ++mi)
            #pragma unroll
            for (int rg = 0; rg < 16; ++rg) {
                psum[mi][rg] += __shfl_xor(psum[mi][rg], off, 64);
                pexp[mi][rg] += __shfl_xor(pexp[mi][rg], off, 64);
            }
    }
    if (rA == 0) {   // lanes 0 / 32 hold h=0 / h=1 row groups
        #pragma unroll
        for (int mi = 0; mi < 2; ++mi)
            #pragma unroll
            for (int rg = 0; rg < 16; ++rg) {
                const int gr = rowBase + wr * 64 + mi * 32
                             + (rg & 3) + 8 * (rg >> 2) + 4 * h;
                atomicAdd(&rowsum[gr], psum[mi][rg]);
                atomicAdd(&rowexp[gr], pexp[mi][rg]);
            }
    }
}

// ---------------- Kernel 3: final reduction + device-side completion --------
__global__ __launch_bounds__(256) void finalize_kernel(
    const float* __restrict__ rowexp, const float* __restrict__ rowsum,
    const float* __restrict__ diag, float* __restrict__ acc, float* __restrict__ out)
{
    const int t = threadIdx.x;
    float ls = 0.f, ds = 0.f, ns = 0.f;
    for (int i = blockIdx.x * 256 + t; i < B_N; i += FIN_BLOCKS * 256) {
        const float d = diag[i];
        ls += __logf(rowexp[i]) - d * 4.0f;   // logsumexp - diag_logit
        ds += d;
        ns += (rowsum[i] - d);
    }
    #pragma unroll
    for (int off = 32; off; off >>= 1) {
        ls += __shfl_down(ls, off, 64);
        ds += __shfl_down(ds, off, 64);
        ns += __shfl_down(ns, off, 64);
    }
    __shared__ float sl[4], sd[4], sn[4];
    if ((t & 63) == 0) { sl[t >> 6] = ls; sd[t >> 6] = ds; sn[t >> 6] = ns; }
    __syncthreads();
    if (t == 0) {
        atomicAdd(acc + 0, sl[0] + sl[1] + sl[2] + sl[3]);
        atomicAdd(acc + 1, sd[0] + sd[1] + sd[2] + sd[3]);
        atomicAdd(acc + 2, sn[0] + sn[1] + sn[2] + sn[3]);
        __threadfence();
        const int done = (int)atomicAdd((unsigned int*)(acc + 3), 1u);
        if (done == FIN_BLOCKS - 1) {
            const float L  = atomicAdd(acc + 0, 0.0f);   // coherent reads
            const float Dm = atomicAdd(acc + 1, 0.0f);
            const float Nn = atomicAdd(acc + 2, 0.0f);
            out[0] = L / (float)B_N;
            out[1] = Dm / (float)B_N;
            out[2] = (Nn / (float)(B_N - 1)) / (float)B_N;
        }
    }
}

// ---------------- Fallback path (small workspace): fp32 vector --------------
__global__ __launch_bounds__(256) void fb_norm(
    const float* __restrict__ A, const float* __restrict__ P,
    float* __restrict__ rna, float* __restrict__ rnp, float* __restrict__ acc)
{
    const int r = blockIdx.x;
    const float* src = blockIdx.y ? P : A;
    const int t = threadIdx.x;
    float ss = 0.f;
    for (int k = t; k < D_K; k += 256) { float v = src[(size_t)r * D_K + k]; ss += v * v; }
    #pragma unroll
    for (int off = 32; off; off >>= 1) ss += __shfl_down(ss, off, 64);
    __shared__ float sred[4];
    if ((t & 63) == 0) sred[t >> 6] = ss;
    __syncthreads();
    if (t == 0) {
        const float rn = rsqrtf(sred[0] + sred[1] + sred[2] + sred[3]);
        (blockIdx.y ? rnp : rna)[r] = rn;
    }
    if (blockIdx.x == 0 && blockIdx.y == 0 && t < 3) acc[t] = 0.0f;
}

__global__ __launch_bounds__(256) void fb_main(
    const float* __restrict__ A, const float* __restrict__ P,
    const float* __restrict__ rna, const float* __restrict__ rnp,
    float* __restrict__ acc)
{
    __shared__ float sa[D_K];
    __shared__ float red[12];
    const int i = blockIdx.x;
    const int t = threadIdx.x;
    const float rn = rna[i];
    for (int k = t; k < D_K; k += 256) sa[k] = A[(size_t)i * D_K + k] * rn;
    __syncthreads();
    const int w = t >> 6, lane = t & 63;
    float we = 0.f, wsum = 0.f, wd = 0.f;
    for (int j = w; j < B_N; j += 4) {
        float dot = 0.f;
        const float* p = P + (size_t)j * D_K;
        for (int k = lane; k < D_K; k += 64) dot += sa[k] * p[k];
        #pragma unroll
        for (int off = 32; off; off >>= 1) dot += __shfl_xor(dot, off, 64);
        const float S = dot * rnp[j];
        we += __expf(S * 4.0f);
        wsum += S;
        if (j == i) wd = S;
    }
    if (lane == 0) { red[w] = we; red[4 + w] = wsum; red[8 + w] = wd; }
    __syncthreads();
    if (t == 0) {
        const float E  = red[0] + red[1] + red[2] + red[3];
        const float Sm = red[4] + red[5] + red[6] + red[7];
        const float Dd = red[8] + red[9] + red[10] + red[11];
        atomicAdd(acc + 0, __logf(E) - 4.0f * Dd);
        atomicAdd(acc + 1, Dd);
        atomicAdd(acc + 2, Sm - Dd);
    }
}

__global__ void fb_fin(const float* __restrict__ acc, float* __restrict__ out)
{
    out[0] = acc[0] / (float)B_N;
    out[1] = acc[1] / (float)B_N;
    out[2] = acc[2] / ((float)(B_N - 1) * (float)B_N);
}

// ---------------------------------------------------------------------------
extern "C" void kernel_launch(void* const* d_in, const int* in_sizes, int n_in,
                              void* d_out, int out_size, void* d_ws, size_t ws_size,
                              hipStream_t stream)
{
    const float* A = (const float*)d_in[0];
    const float* P = (const float*)d_in[1];
    float* out = (float*)d_out;
    char* ws = (char*)d_ws;

    const size_t AF8_OFF  = 0;
    const size_t PF8_OFF  = AF8_OFF + (size_t)B_N * KPAD;
    const size_t REXP_OFF = PF8_OFF + (size_t)B_N * KPAD;
    const size_t RSUM_OFF = REXP_OFF + (size_t)B_N * sizeof(float);
    const size_t DIAG_OFF = RSUM_OFF + (size_t)B_N * sizeof(float);
    const size_t ACC_OFF  = DIAG_OFF + (size_t)B_N * sizeof(float);
    const size_t MAIN_REQ = ACC_OFF + 16;

    if (ws_size >= MAIN_REQ) {
        unsigned char* Af8 = (unsigned char*)(ws + AF8_OFF);
        unsigned char* Pf8 = (unsigned char*)(ws + PF8_OFF);
        float* rowexp = (float*)(ws + REXP_OFF);
        float* rowsum = (float*)(ws + RSUM_OFF);
        float* diag   = (float*)(ws + DIAG_OFF);
        float* acc    = (float*)(ws + ACC_OFF);

        normalize_kernel<<<dim3(B_N / 8, 2), 256, 0, stream>>>(A, P, Af8, Pf8,
                                                               rowexp, rowsum, acc);
        gemm_fused_kernel<<<dim3(B_N / BM, COL_CHUNKS), 256, 0, stream>>>(
            Af8, Pf8, rowexp, rowsum, diag);
        finalize_kernel<<<FIN_BLOCKS, 256, 0, stream>>>(rowexp, rowsum, diag, acc, out);
    } else {
        // slow-but-correct fp32 fallback (needs ~96 KB ws)
        float* rna = (float*)ws;
        float* rnp = rna + B_N;
        float* acc = rnp + B_N;
        fb_norm<<<dim3(B_N, 2), 256, 0, stream>>>(A, P, rna, rnp, acc);
        fb_main<<<B_N, 256, 0, stream>>>(A, P, rna, rnp, acc);
        fb_fin<<<1, 1, 0, stream>>>(acc, out);
    }
}